// Round 2
// baseline (690.422 us; speedup 1.0000x reference)
//
#include <hip/hip_runtime.h>
#include <math.h>

#define EPS_BN 1e-5f

// ---------------------------------------------------------------------------
// GEMM + BatchNorm(eval) + ReLU (fp32 vector ALU; no fp32 MFMA on CDNA4)
// out[M][256] = relu( (A[M][K] @ W[256][K]^T + bias - mean) * g/sqrt(var+eps) + beta )
// Tiling: 128x128 block tile, BK=16, 256 threads, 8x8 per thread (split 4+4).
// ---------------------------------------------------------------------------
__global__ __launch_bounds__(256) void gemm_bn_relu(
    const float* __restrict__ A,     // [M][K]
    const float* __restrict__ W,     // [256][K]
    const float* __restrict__ bias,
    const float* __restrict__ gamma,
    const float* __restrict__ beta,
    const float* __restrict__ mean,
    const float* __restrict__ var,
    float* __restrict__ out,         // [M][256]
    int M, int K)
{
    constexpr int BK = 16;
    constexpr int BMP = 132;   // padded leading dim (128 + 4) breaks write conflicts
    __shared__ __align__(16) float As[BK][BMP];
    __shared__ __align__(16) float Bs[BK][BMP];

    const int tid = threadIdx.x;
    const int bn  = blockIdx.x;    // 0..1  (N=256 / 128)
    const int bm  = blockIdx.y;    // M / 128
    const int tx  = tid & 15;
    const int ty  = tid >> 4;

    float acc[8][8];
#pragma unroll
    for (int i = 0; i < 8; i++)
#pragma unroll
        for (int j = 0; j < 8; j++) acc[i][j] = 0.f;

    // staging: each thread loads 2 float4 of A and 2 float4 of B
    const int srow = tid >> 1;           // 0..127
    const int skv  = (tid & 1) * 8;      // float offset within the 16-wide k slab

    const float* Ab = A + (size_t)(bm * 128 + srow) * K;
    const float* Wb = W + (size_t)(bn * 128 + srow) * K;

    for (int k0 = 0; k0 < K; k0 += BK) {
        float4 a0 = *(const float4*)(Ab + k0 + skv);
        float4 a1 = *(const float4*)(Ab + k0 + skv + 4);
        float4 b0 = *(const float4*)(Wb + k0 + skv);
        float4 b1 = *(const float4*)(Wb + k0 + skv + 4);

        __syncthreads();   // previous iteration's LDS reads complete
        As[skv + 0][srow] = a0.x; As[skv + 1][srow] = a0.y;
        As[skv + 2][srow] = a0.z; As[skv + 3][srow] = a0.w;
        As[skv + 4][srow] = a1.x; As[skv + 5][srow] = a1.y;
        As[skv + 6][srow] = a1.z; As[skv + 7][srow] = a1.w;
        Bs[skv + 0][srow] = b0.x; Bs[skv + 1][srow] = b0.y;
        Bs[skv + 2][srow] = b0.z; Bs[skv + 3][srow] = b0.w;
        Bs[skv + 4][srow] = b1.x; Bs[skv + 5][srow] = b1.y;
        Bs[skv + 6][srow] = b1.z; Bs[skv + 7][srow] = b1.w;
        __syncthreads();

#pragma unroll 4
        for (int kk = 0; kk < BK; kk++) {
            const float4* Ar = (const float4*)&As[kk][0];
            const float4* Br = (const float4*)&Bs[kk][0];
            float4 af0 = Ar[ty];        // rows ty*4 .. +3
            float4 af1 = Ar[16 + ty];   // rows 64+ty*4 .. +3
            float4 bf0 = Br[tx];
            float4 bf1 = Br[16 + tx];
            float a_[8] = {af0.x, af0.y, af0.z, af0.w, af1.x, af1.y, af1.z, af1.w};
            float b_[8] = {bf0.x, bf0.y, bf0.z, bf0.w, bf1.x, bf1.y, bf1.z, bf1.w};
#pragma unroll
            for (int i = 0; i < 8; i++)
#pragma unroll
                for (int j = 0; j < 8; j++) acc[i][j] += a_[i] * b_[j];
        }
    }

    // epilogue: fused bias + BN + ReLU
    float scale[8], shift[8];
#pragma unroll
    for (int j = 0; j < 8; j++) {
        int n = bn * 128 + ((j < 4) ? (tx * 4 + j) : (64 + tx * 4 + j - 4));
        float s = gamma[n] / sqrtf(var[n] + EPS_BN);
        scale[j] = s;
        shift[j] = beta[n] + (bias[n] - mean[n]) * s;
    }
#pragma unroll
    for (int i = 0; i < 8; i++) {
        int r = bm * 128 + ((i < 4) ? (ty * 4 + i) : (64 + ty * 4 + i - 4));
        float4 v0, v1;
        v0.x = fmaxf(acc[i][0] * scale[0] + shift[0], 0.f);
        v0.y = fmaxf(acc[i][1] * scale[1] + shift[1], 0.f);
        v0.z = fmaxf(acc[i][2] * scale[2] + shift[2], 0.f);
        v0.w = fmaxf(acc[i][3] * scale[3] + shift[3], 0.f);
        v1.x = fmaxf(acc[i][4] * scale[4] + shift[4], 0.f);
        v1.y = fmaxf(acc[i][5] * scale[5] + shift[5], 0.f);
        v1.z = fmaxf(acc[i][6] * scale[6] + shift[6], 0.f);
        v1.w = fmaxf(acc[i][7] * scale[7] + shift[7], 0.f);
        *(float4*)(out + (size_t)r * 256 + bn * 128 + tx * 4)      = v0;
        *(float4*)(out + (size_t)r * 256 + bn * 128 + 64 + tx * 4) = v1;
    }
}

// ---------------------------------------------------------------------------
// 3-NN inverse-distance interpolation, accumulated into out (which holds feats2)
// One block = 256 targets of one batch. xyz1 + |s|^2 staged in LDS as float4.
//
// CRITICAL numerics: the np reference computes squared distances in fp32 via
//   d = (|t|^2 - 2*t.s) + |s|^2
// with unfused IEEE fp32 ops. All inner reductions have length 3, so every
// association order collapses to ((p0+p1)+p2). We replicate BIT-EXACTLY with
// __fmul_rn/__fadd_rn/__fsub_rn (prevents FMA contraction) so that neighbor
// selection (incl. near-ties) matches the reference. Strict-< insertion keeps
// the lowest index among equal values = lax.top_k stable tie-break.
// ---------------------------------------------------------------------------
__global__ __launch_bounds__(256) void knn_interp(
    const float* __restrict__ xyz1,   // [4][4096][3] sources
    const float* __restrict__ xyz2,   // [4][16384][3] targets
    const float* __restrict__ feats1, // [4*4096][256]
    float* __restrict__ out)          // [4*16384][256], preloaded with feats2
{
    __shared__ __align__(16) float4 s1[4096];  // x, y, z, |s|^2
    __shared__ int   sidx[3][256];
    __shared__ float swt[3][256];

    const int tid   = threadIdx.x;
    const int b     = blockIdx.x >> 6;   // batch
    const int chunk = blockIdx.x & 63;   // 256-target chunk within batch

    const float* src = xyz1 + (size_t)b * 4096 * 3;
    for (int i = tid; i < 4096; i += 256) {
        float x = src[i * 3 + 0];
        float y = src[i * 3 + 1];
        float z = src[i * 3 + 2];
        float ss = __fadd_rn(__fadd_rn(__fmul_rn(x, x), __fmul_rn(y, y)),
                             __fmul_rn(z, z));
        s1[i] = make_float4(x, y, z, ss);
    }
    __syncthreads();

    const int t = chunk * 256 + tid;       // target within batch
    const int g = b * 16384 + t;           // global target row
    const float tx = xyz2[(size_t)g * 3 + 0];
    const float ty = xyz2[(size_t)g * 3 + 1];
    const float tz = xyz2[(size_t)g * 3 + 2];
    const float sumT = __fadd_rn(__fadd_rn(__fmul_rn(tx, tx), __fmul_rn(ty, ty)),
                                 __fmul_rn(tz, tz));

    float d0 = INFINITY, d1 = INFINITY, d2 = INFINITY;
    int   i0 = 0,        i1 = 0,        i2 = 0;

#pragma unroll 8
    for (int i = 0; i < 4096; i++) {
        float4 s = s1[i];
        float dot = __fadd_rn(__fadd_rn(__fmul_rn(tx, s.x), __fmul_rn(ty, s.y)),
                              __fmul_rn(tz, s.z));
        float d = __fadd_rn(__fsub_rn(sumT, __fmul_rn(2.0f, dot)), s.w);
        if (d < d2) {
            if (d < d1) {
                d2 = d1; i2 = i1;
                if (d < d0) { d1 = d0; i1 = i0; d0 = d; i0 = i; }
                else        { d1 = d;  i1 = i; }
            } else { d2 = d; i2 = i; }
        }
    }

    float w0 = 1.0f / __fadd_rn(d0, 1e-8f);
    float w1 = 1.0f / __fadd_rn(d1, 1e-8f);
    float w2 = 1.0f / __fadd_rn(d2, 1e-8f);
    float ws = __fadd_rn(__fadd_rn(w0, w1), w2);
    swt[0][tid] = w0 / ws;
    swt[1][tid] = w1 / ws;
    swt[2][tid] = w2 / ws;
    sidx[0][tid] = i0; sidx[1][tid] = i1; sidx[2][tid] = i2;
    __syncthreads();

    // phase 2: wave-per-target, fully coalesced float4 gather/accumulate
    const int wv   = tid >> 6;
    const int lane = tid & 63;
    const float4* F1 = (const float4*)feats1 + (size_t)b * 4096 * 64;
    float4* O = (float4*)out + ((size_t)b * 16384 + (size_t)chunk * 256) * 64;

    for (int tt = wv; tt < 256; tt += 4) {
        const int j0 = sidx[0][tt], j1 = sidx[1][tt], j2 = sidx[2][tt];
        const float u0 = swt[0][tt], u1 = swt[1][tt], u2 = swt[2][tt];
        float4 f0 = F1[(size_t)j0 * 64 + lane];
        float4 f1 = F1[(size_t)j1 * 64 + lane];
        float4 f2 = F1[(size_t)j2 * 64 + lane];
        float4 o  = O[(size_t)tt * 64 + lane];
        o.x += u0 * f0.x + u1 * f1.x + u2 * f2.x;
        o.y += u0 * f0.y + u1 * f1.y + u2 * f2.y;
        o.z += u0 * f0.z + u1 * f1.z + u2 * f2.z;
        o.w += u0 * f0.w + u1 * f1.w + u2 * f2.w;
        O[(size_t)tt * 64 + lane] = o;
    }
}

extern "C" void kernel_launch(void* const* d_in, const int* in_sizes, int n_in,
                              void* d_out, int out_size, void* d_ws, size_t ws_size,
                              hipStream_t stream) {
    const float* xyz1    = (const float*)d_in[0];
    const float* points1 = (const float*)d_in[1];
    const float* xyz2    = (const float*)d_in[2];
    const float* points2 = (const float*)d_in[3];
    const float* W1  = (const float*)d_in[4];
    const float* b1  = (const float*)d_in[5];
    const float* g1  = (const float*)d_in[6];
    const float* be1 = (const float*)d_in[7];
    const float* m1  = (const float*)d_in[8];
    const float* v1  = (const float*)d_in[9];
    const float* W2  = (const float*)d_in[10];
    const float* b2  = (const float*)d_in[11];
    const float* g2  = (const float*)d_in[12];
    const float* be2 = (const float*)d_in[13];
    const float* m2  = (const float*)d_in[14];
    const float* v2  = (const float*)d_in[15];

    float* feats1 = (float*)d_ws;          // 16384*256*4 = 16 MB scratch
    float* outp   = (float*)d_out;         // 65536*256 floats

    dim3 blk(256);
    // feats1 = relu(BN(points1 @ W1^T + b1))   [4*4096, 256]
    gemm_bn_relu<<<dim3(2, 128), blk, 0, stream>>>(points1, W1, b1, g1, be1, m1, v1,
                                                   feats1, 16384, 512);
    // out = feats2 = relu(BN(points2 @ W2^T + b2))   [4*16384, 256]
    gemm_bn_relu<<<dim3(2, 512), blk, 0, stream>>>(points2, W2, b2, g2, be2, m2, v2,
                                                   outp, 65536, 256);
    // out += interp3(xyz2 <- xyz1, feats1)
    knn_interp<<<dim3(256), blk, 0, stream>>>(xyz1, xyz2, feats1, outp);
}

// Round 3
// 381.872 us; speedup vs baseline: 1.8080x; 1.8080x over previous
//
#include <hip/hip_runtime.h>
#include <math.h>

#define EPS_BN 1e-5f

typedef __attribute__((ext_vector_type(8))) short bf16x8;
typedef __attribute__((ext_vector_type(4))) float f32x4;

// ---------------------------------------------------------------------------
// async global->LDS, 16B per lane
// ---------------------------------------------------------------------------
__device__ __forceinline__ void gld_lds16(const void* g, void* l) {
    __builtin_amdgcn_global_load_lds(
        (const __attribute__((address_space(1))) unsigned int*)g,
        (__attribute__((address_space(3))) unsigned int*)l, 16, 0, 0);
}

__device__ __forceinline__ unsigned short f2bf(float f) {  // RNE fp32->bf16
    unsigned u = __float_as_uint(f);
    return (unsigned short)((u + 0x7FFFu + ((u >> 16) & 1u)) >> 16);
}

// ---------------------------------------------------------------------------
// Convert fp32 [M][K] -> bf16 tile-packed swizzled:
//   dst[mblk][slab][r][granule-rotated 64B row],  mblk=m/128, slab=k/32, r=m%128
//   element (r,k): 16B granule g = ((k>>3) + (r>>1)) & 3  at byte r*64 + g*16.
// Rotation makes the MFMA fragment ds_read_b128 pattern 2-lanes/bank (free).
// One thread per (row, k-octet): reads 32B, writes 16B.
// ---------------------------------------------------------------------------
__global__ __launch_bounds__(256) void convert_swz(
    const float* __restrict__ src, unsigned short* __restrict__ dst,
    int K8log, int nslab)
{
    const int gid = blockIdx.x * 256 + threadIdx.x;
    const int m  = gid >> K8log;
    const int ko = gid & ((1 << K8log) - 1);
    const float4* s = (const float4*)src + ((size_t)m << (K8log + 1)) + ko * 2;
    float4 f0 = s[0];
    float4 f1 = s[1];
    const int mblk = m >> 7, r = m & 127;
    const int slab = ko >> 2, o = ko & 3;
    const int g = (o + (r >> 1)) & 3;
    unsigned short h[8] = {f2bf(f0.x), f2bf(f0.y), f2bf(f0.z), f2bf(f0.w),
                           f2bf(f1.x), f2bf(f1.y), f2bf(f1.z), f2bf(f1.w)};
    *(uint4*)(dst + ((size_t)(mblk * nslab + slab)) * 4096 + r * 32 + g * 8) =
        *(uint4*)h;
}

// ---------------------------------------------------------------------------
// bf16 MFMA GEMM + BN + ReLU.  C[M][256] = relu(BN(A[M][K] @ W[256][K]^T))
// A,W pre-packed/swizzled by convert_swz. 128x128 tile, BK=32, 4 waves,
// each wave 4x4 subtiles of mfma_f32_16x16x32_bf16 (verified m91 layout:
// A[m=lane&15][k=quad*8+j], B[k][n=lane&15], D col=lane&15 row=quad*4+reg).
// ---------------------------------------------------------------------------
__global__ __launch_bounds__(256) void gemm_bf16_bn_relu(
    const unsigned short* __restrict__ Ap,   // [M/128][K/32][128][32] swizzled
    const unsigned short* __restrict__ Bp,   // [2][K/32][128][32] swizzled
    const float* __restrict__ bias,
    const float* __restrict__ gamma,
    const float* __restrict__ beta,
    const float* __restrict__ mean,
    const float* __restrict__ var,
    float* __restrict__ out, int M, int K)
{
    __shared__ __align__(16) unsigned short As[4096];   // 8 KB
    __shared__ __align__(16) unsigned short Bs[4096];   // 8 KB

    const int tid  = threadIdx.x;
    const int w    = tid >> 6;
    const int lane = tid & 63;
    const int q    = lane >> 4;
    const int rl   = lane & 15;
    const int wm   = w >> 1, wn = w & 1;
    const int bn   = blockIdx.x, bm = blockIdx.y;
    const int nslab = K >> 5;

    f32x4 acc[4][4];
#pragma unroll
    for (int i = 0; i < 4; i++)
#pragma unroll
        for (int j = 0; j < 4; j++) acc[i][j] = (f32x4){0.f, 0.f, 0.f, 0.f};

    const unsigned short* Ab = Ap + (size_t)bm * nslab * 4096;
    const unsigned short* Bb = Bp + (size_t)bn * nslab * 4096;
    const int c0 = 2 * w;               // this wave's two 1KB chunks
    const int l8 = lane * 8;

    // precompute fragment LDS indices (swizzled)
    int aidx[4], bidx[4];
#pragma unroll
    for (int i = 0; i < 4; i++) {
        int rr = wm * 64 + i * 16 + rl;
        aidx[i] = rr * 32 + ((q + (rr >> 1)) & 3) * 8;
        int nn = wn * 64 + i * 16 + rl;
        bidx[i] = nn * 32 + ((q + (nn >> 1)) & 3) * 8;
    }

    for (int s = 0; s < nslab; s++) {
        __syncthreads();     // previous iteration's LDS reads complete
        const unsigned short* a = Ab + (size_t)s * 4096;
        const unsigned short* b = Bb + (size_t)s * 4096;
        gld_lds16(a + (c0 + 0) * 512 + l8, &As[(c0 + 0) * 512 + l8]);
        gld_lds16(a + (c0 + 1) * 512 + l8, &As[(c0 + 1) * 512 + l8]);
        gld_lds16(b + (c0 + 0) * 512 + l8, &Bs[(c0 + 0) * 512 + l8]);
        gld_lds16(b + (c0 + 1) * 512 + l8, &Bs[(c0 + 1) * 512 + l8]);
        __syncthreads();     // drains vmcnt before barrier

        bf16x8 af[4], bf[4];
#pragma unroll
        for (int i = 0; i < 4; i++) af[i] = *(const bf16x8*)&As[aidx[i]];
#pragma unroll
        for (int j = 0; j < 4; j++) bf[j] = *(const bf16x8*)&Bs[bidx[j]];
#pragma unroll
        for (int i = 0; i < 4; i++)
#pragma unroll
            for (int j = 0; j < 4; j++)
                acc[i][j] = __builtin_amdgcn_mfma_f32_16x16x32_bf16(
                    af[i], bf[j], acc[i][j], 0, 0, 0);
    }

    // epilogue: BN + ReLU, scalar stores (16-lane 64B segments)
    const int gm0 = bm * 128 + wm * 64;
    const int gn0 = bn * 128 + wn * 64;
#pragma unroll
    for (int j = 0; j < 4; j++) {
        int n = gn0 + j * 16 + rl;
        float sc = gamma[n] / sqrtf(var[n] + EPS_BN);
        float sh = beta[n] + (bias[n] - mean[n]) * sc;
#pragma unroll
        for (int i = 0; i < 4; i++) {
            int m0 = gm0 + i * 16 + q * 4;
#pragma unroll
            for (int t = 0; t < 4; t++) {
                float v = fmaxf(acc[i][j][t] * sc + sh, 0.f);
                out[(size_t)(m0 + t) * 256 + n] = v;
            }
        }
    }
}

// ---------------------------------------------------------------------------
// KNN phase 1: per (batch, 256-target chunk, source-quarter) block, scan 1024
// sources, emit per-part top-3 (d, idx). Bit-exact fp32 vs np reference:
//   d = (sumT - 2*dot) + sumS, all ops unfused RN. Sources pre-doubled
//   (2x,2y,2z): rn(2a*b)=2*rn(a*b), scaling by 2 commutes exactly with all
//   rounding, so d is bit-identical to the reference formula.
// ---------------------------------------------------------------------------
__global__ __launch_bounds__(256) void knn_select(
    const float* __restrict__ xyz1, const float* __restrict__ xyz2,
    float* __restrict__ cand_d, int* __restrict__ cand_i)
{
    __shared__ __align__(16) float4 s1[1024];   // 2x, 2y, 2z, |s|^2

    const int tid   = threadIdx.x;
    const int blk   = blockIdx.x;       // 0..1023
    const int part  = blk & 3;
    const int chunk = (blk >> 2) & 63;
    const int b     = blk >> 8;

    const float* src = xyz1 + ((size_t)b * 4096 + part * 1024) * 3;
    for (int i = tid; i < 1024; i += 256) {
        float x = src[i * 3 + 0], y = src[i * 3 + 1], z = src[i * 3 + 2];
        float ss = __fadd_rn(__fadd_rn(__fmul_rn(x, x), __fmul_rn(y, y)),
                             __fmul_rn(z, z));
        s1[i] = make_float4(x + x, y + y, z + z, ss);
    }
    __syncthreads();

    const int t = chunk * 256 + tid;
    const int g = b * 16384 + t;
    const float tx = xyz2[(size_t)g * 3 + 0];
    const float ty = xyz2[(size_t)g * 3 + 1];
    const float tz = xyz2[(size_t)g * 3 + 2];
    const float sumT = __fadd_rn(__fadd_rn(__fmul_rn(tx, tx), __fmul_rn(ty, ty)),
                                 __fmul_rn(tz, tz));

    float d0 = INFINITY, d1 = INFINITY, d2 = INFINITY;
    int   i0 = 0,        i1 = 0,        i2 = 0;

#pragma unroll 4
    for (int i = 0; i < 1024; i++) {
        float4 s = s1[i];
        float dot2 = __fadd_rn(__fadd_rn(__fmul_rn(tx, s.x), __fmul_rn(ty, s.y)),
                               __fmul_rn(tz, s.z));                 // = 2*dot exactly
        float d = __fadd_rn(__fsub_rn(sumT, dot2), s.w);
        if (d < d2) {           // rare: wave-level execz skip
            if (d < d1) {
                d2 = d1; i2 = i1;
                if (d < d0) { d1 = d0; i1 = i0; d0 = d; i0 = i; }
                else        { d1 = d;  i1 = i; }
            } else { d2 = d; i2 = i; }
        }
    }

    const size_t base = ((size_t)g * 4 + part) * 3;
    cand_d[base + 0] = d0; cand_d[base + 1] = d1; cand_d[base + 2] = d2;
    cand_i[base + 0] = part * 1024 + i0;
    cand_i[base + 1] = part * 1024 + i1;
    cand_i[base + 2] = part * 1024 + i2;
}

// ---------------------------------------------------------------------------
// KNN phase 2: merge 4x3 candidates -> final top-3 + normalized weights.
// Candidates arrive part-major (ascending global index), each part sorted
// ascending-d stable; strict-< insertion reproduces lax.top_k stable ties.
// ---------------------------------------------------------------------------
__global__ __launch_bounds__(256) void knn_merge(
    const float* __restrict__ cand_d, const int* __restrict__ cand_i,
    float* __restrict__ w3, int* __restrict__ idx3)
{
    const int g = blockIdx.x * 256 + threadIdx.x;   // 0..65535
    float d0 = INFINITY, d1 = INFINITY, d2 = INFINITY;
    int   i0 = 0,        i1 = 0,        i2 = 0;
#pragma unroll
    for (int p = 0; p < 12; p++) {
        float d = cand_d[(size_t)g * 12 + p];
        int  ix = cand_i[(size_t)g * 12 + p];
        if (d < d2) {
            if (d < d1) {
                d2 = d1; i2 = i1;
                if (d < d0) { d1 = d0; i1 = i0; d0 = d; i0 = ix; }
                else        { d1 = d;  i1 = ix; }
            } else { d2 = d; i2 = ix; }
        }
    }
    float w0 = 1.0f / __fadd_rn(d0, 1e-8f);
    float w1 = 1.0f / __fadd_rn(d1, 1e-8f);
    float w2 = 1.0f / __fadd_rn(d2, 1e-8f);
    float ws = __fadd_rn(__fadd_rn(w0, w1), w2);
    w3[(size_t)g * 3 + 0] = w0 / ws;
    w3[(size_t)g * 3 + 1] = w1 / ws;
    w3[(size_t)g * 3 + 2] = w2 / ws;
    idx3[(size_t)g * 3 + 0] = i0;
    idx3[(size_t)g * 3 + 1] = i1;
    idx3[(size_t)g * 3 + 2] = i2;
}

// ---------------------------------------------------------------------------
// KNN phase 3: wave-per-target gather/accumulate. out already holds feats2.
// ---------------------------------------------------------------------------
__global__ __launch_bounds__(256) void knn_gather(
    const float* __restrict__ feats1, const float* __restrict__ w3,
    const int* __restrict__ idx3, float* __restrict__ out)
{
    const int w    = threadIdx.x >> 6;
    const int lane = threadIdx.x & 63;
    const int tbase = (blockIdx.x * 4 + w) * 16;   // 16 targets per wave

#pragma unroll 4
    for (int k = 0; k < 16; k++) {
        const int g = tbase + k;
        const int b = g >> 14;
        const int j0 = idx3[(size_t)g * 3 + 0];
        const int j1 = idx3[(size_t)g * 3 + 1];
        const int j2 = idx3[(size_t)g * 3 + 2];
        const float u0 = w3[(size_t)g * 3 + 0];
        const float u1 = w3[(size_t)g * 3 + 1];
        const float u2 = w3[(size_t)g * 3 + 2];
        const float4* F1 = (const float4*)feats1 + (size_t)b * 4096 * 64;
        float4 f0 = F1[(size_t)j0 * 64 + lane];
        float4 f1 = F1[(size_t)j1 * 64 + lane];
        float4 f2 = F1[(size_t)j2 * 64 + lane];
        float4* O = (float4*)out + (size_t)g * 64 + lane;
        float4 o = *O;
        o.x += u0 * f0.x + u1 * f1.x + u2 * f2.x;
        o.y += u0 * f0.y + u1 * f1.y + u2 * f2.y;
        o.z += u0 * f0.z + u1 * f1.z + u2 * f2.z;
        o.w += u0 * f0.w + u1 * f1.w + u2 * f2.w;
        *O = o;
    }
}

extern "C" void kernel_launch(void* const* d_in, const int* in_sizes, int n_in,
                              void* d_out, int out_size, void* d_ws, size_t ws_size,
                              hipStream_t stream) {
    const float* xyz1    = (const float*)d_in[0];
    const float* points1 = (const float*)d_in[1];
    const float* xyz2    = (const float*)d_in[2];
    const float* points2 = (const float*)d_in[3];
    const float* W1  = (const float*)d_in[4];
    const float* b1  = (const float*)d_in[5];
    const float* g1  = (const float*)d_in[6];
    const float* be1 = (const float*)d_in[7];
    const float* m1  = (const float*)d_in[8];
    const float* v1  = (const float*)d_in[9];
    const float* W2  = (const float*)d_in[10];
    const float* b2  = (const float*)d_in[11];
    const float* g2  = (const float*)d_in[12];
    const float* be2 = (const float*)d_in[13];
    const float* m2  = (const float*)d_in[14];
    const float* v2  = (const float*)d_in[15];

    const size_t MB = 1u << 20;
    char* ws = (char*)d_ws;
    float*          feats1 = (float*)(ws);                 // 16 MB
    unsigned short* A1p    = (unsigned short*)(ws + 16 * MB);   // 16 MB
    unsigned short* A2p    = (unsigned short*)(ws + 32 * MB);   // 32 MB
    unsigned short* W1p    = (unsigned short*)(ws + 64 * MB);   // 0.5 MB
    unsigned short* W2p    = (unsigned short*)(ws + 65 * MB);   // 0.25 MB
    float*          cand_d = (float*)(ws + 66 * MB);            // 3 MB
    int*            cand_i = (int*)(ws + 69 * MB);              // 3 MB
    float*          w3     = (float*)(ws + 72 * MB);            // 0.75 MB
    int*            idx3   = (int*)(ws + 73 * MB);              // 0.75 MB
    float* outp = (float*)d_out;

    dim3 blk(256);
    // bf16 pack+swizzle: A1 [16384][512], A2 [65536][256], W1 [256][512], W2 [256][256]
    convert_swz<<<4096, blk, 0, stream>>>(points1, A1p, 6, 16);
    convert_swz<<<8192, blk, 0, stream>>>(points2, A2p, 5, 8);
    convert_swz<<<64,   blk, 0, stream>>>(W1, W1p, 6, 16);
    convert_swz<<<32,   blk, 0, stream>>>(W2, W2p, 5, 8);

    // feats1 = relu(BN(points1 @ W1^T));  out = relu(BN(points2 @ W2^T))
    gemm_bf16_bn_relu<<<dim3(2, 128), blk, 0, stream>>>(A1p, W1p, b1, g1, be1, m1, v1,
                                                        feats1, 16384, 512);
    gemm_bf16_bn_relu<<<dim3(2, 512), blk, 0, stream>>>(A2p, W2p, b2, g2, be2, m2, v2,
                                                        outp, 65536, 256);

    // out += interp3(xyz2 <- xyz1, feats1)
    knn_select<<<1024, blk, 0, stream>>>(xyz1, xyz2, cand_d, cand_i);
    knn_merge<<<256, blk, 0, stream>>>(cand_d, cand_i, w3, idx3);
    knn_gather<<<1024, blk, 0, stream>>>(feats1, w3, idx3, outp);
}

// Round 4
// 367.380 us; speedup vs baseline: 1.8793x; 1.0394x over previous
//
#include <hip/hip_runtime.h>
#include <math.h>

#define EPS_BN 1e-5f

typedef __attribute__((ext_vector_type(8))) short bf16x8;
typedef __attribute__((ext_vector_type(4))) float f32x4;

// ---------------------------------------------------------------------------
// async global->LDS, 16B per lane
// ---------------------------------------------------------------------------
__device__ __forceinline__ void gld_lds16(const void* g, void* l) {
    __builtin_amdgcn_global_load_lds(
        (const __attribute__((address_space(1))) unsigned int*)g,
        (__attribute__((address_space(3))) unsigned int*)l, 16, 0, 0);
}

__device__ __forceinline__ unsigned short f2bf(float f) {  // RNE fp32->bf16
    unsigned u = __float_as_uint(f);
    return (unsigned short)((u + 0x7FFFu + ((u >> 16) & 1u)) >> 16);
}

// ---------------------------------------------------------------------------
// fp32 [M][K] -> bf16 tile-packed swizzled (see R3 notes): granule rotation
// g=((k>>3)+(r>>1))&3 makes MFMA fragment ds_read_b128 2-lanes/bank (free).
// ---------------------------------------------------------------------------
__device__ __forceinline__ void conv_body(
    const float* __restrict__ src, unsigned short* __restrict__ dst,
    int blk, int tid, int K8log, int nslab)
{
    const int gid = blk * 256 + tid;
    const int m  = gid >> K8log;
    const int ko = gid & ((1 << K8log) - 1);
    const float4* s = (const float4*)src + ((size_t)m << (K8log + 1)) + ko * 2;
    float4 f0 = s[0];
    float4 f1 = s[1];
    const int mblk = m >> 7, r = m & 127;
    const int slab = ko >> 2, o = ko & 3;
    const int g = (o + (r >> 1)) & 3;
    unsigned short h[8] = {f2bf(f0.x), f2bf(f0.y), f2bf(f0.z), f2bf(f0.w),
                           f2bf(f1.x), f2bf(f1.y), f2bf(f1.z), f2bf(f1.w)};
    *(uint4*)(dst + ((size_t)(mblk * nslab + slab)) * 4096 + r * 32 + g * 8) =
        *(uint4*)h;
}

// ---------------------------------------------------------------------------
// One fused prep dispatch: bf16 pack A1/A2/W1/W2 + xyz packing.
//   sxyz1[i] = (2x, 2y, 2z, |s|^2)   (doubling is exact; rn(2a*b)=2*rn(a*b))
//   txyz2[i] = ( x,  y,  z, |t|^2)
// All |.|^2 with unfused RN ops, bit-exact vs np fp32.
// ---------------------------------------------------------------------------
__global__ __launch_bounds__(256) void prep_all(
    const float* __restrict__ p1, const float* __restrict__ p2,
    const float* __restrict__ w1, const float* __restrict__ w2,
    unsigned short* __restrict__ A1p, unsigned short* __restrict__ A2p,
    unsigned short* __restrict__ W1p, unsigned short* __restrict__ W2p,
    const float* __restrict__ xyz1, const float* __restrict__ xyz2,
    float4* __restrict__ sxyz1, float4* __restrict__ txyz2)
{
    const int blk = blockIdx.x, tid = threadIdx.x;
    if (blk < 4096)        conv_body(p1, A1p, blk,         tid, 6, 16);
    else if (blk < 12288)  conv_body(p2, A2p, blk - 4096,  tid, 5, 8);
    else if (blk < 12352)  conv_body(w1, W1p, blk - 12288, tid, 6, 16);
    else if (blk < 12384)  conv_body(w2, W2p, blk - 12352, tid, 5, 8);
    else if (blk < 12448) {                       // xyz1 pack: 16384 sources
        int i = (blk - 12384) * 256 + tid;
        float x = xyz1[i * 3 + 0], y = xyz1[i * 3 + 1], z = xyz1[i * 3 + 2];
        float ss = __fadd_rn(__fadd_rn(__fmul_rn(x, x), __fmul_rn(y, y)),
                             __fmul_rn(z, z));
        sxyz1[i] = make_float4(x + x, y + y, z + z, ss);
    } else {                                      // xyz2 pack: 65536 targets
        int i = (blk - 12448) * 256 + tid;
        float x = xyz2[i * 3 + 0], y = xyz2[i * 3 + 1], z = xyz2[i * 3 + 2];
        float st = __fadd_rn(__fadd_rn(__fmul_rn(x, x), __fmul_rn(y, y)),
                             __fmul_rn(z, z));
        txyz2[i] = make_float4(x, y, z, st);
    }
}

// ---------------------------------------------------------------------------
// bf16 MFMA GEMM + BN + ReLU (unchanged from R3; verified).
// ---------------------------------------------------------------------------
__global__ __launch_bounds__(256) void gemm_bf16_bn_relu(
    const unsigned short* __restrict__ Ap,
    const unsigned short* __restrict__ Bp,
    const float* __restrict__ bias,
    const float* __restrict__ gamma,
    const float* __restrict__ beta,
    const float* __restrict__ mean,
    const float* __restrict__ var,
    float* __restrict__ out, int M, int K)
{
    __shared__ __align__(16) unsigned short As[4096];
    __shared__ __align__(16) unsigned short Bs[4096];

    const int tid  = threadIdx.x;
    const int w    = tid >> 6;
    const int lane = tid & 63;
    const int q    = lane >> 4;
    const int rl   = lane & 15;
    const int wm   = w >> 1, wn = w & 1;
    const int bn   = blockIdx.x, bm = blockIdx.y;
    const int nslab = K >> 5;

    f32x4 acc[4][4];
#pragma unroll
    for (int i = 0; i < 4; i++)
#pragma unroll
        for (int j = 0; j < 4; j++) acc[i][j] = (f32x4){0.f, 0.f, 0.f, 0.f};

    const unsigned short* Ab = Ap + (size_t)bm * nslab * 4096;
    const unsigned short* Bb = Bp + (size_t)bn * nslab * 4096;
    const int c0 = 2 * w;
    const int l8 = lane * 8;

    int aidx[4], bidx[4];
#pragma unroll
    for (int i = 0; i < 4; i++) {
        int rr = wm * 64 + i * 16 + rl;
        aidx[i] = rr * 32 + ((q + (rr >> 1)) & 3) * 8;
        int nn = wn * 64 + i * 16 + rl;
        bidx[i] = nn * 32 + ((q + (nn >> 1)) & 3) * 8;
    }

    for (int s = 0; s < nslab; s++) {
        __syncthreads();
        const unsigned short* a = Ab + (size_t)s * 4096;
        const unsigned short* b = Bb + (size_t)s * 4096;
        gld_lds16(a + (c0 + 0) * 512 + l8, &As[(c0 + 0) * 512 + l8]);
        gld_lds16(a + (c0 + 1) * 512 + l8, &As[(c0 + 1) * 512 + l8]);
        gld_lds16(b + (c0 + 0) * 512 + l8, &Bs[(c0 + 0) * 512 + l8]);
        gld_lds16(b + (c0 + 1) * 512 + l8, &Bs[(c0 + 1) * 512 + l8]);
        __syncthreads();

        bf16x8 af[4], bf[4];
#pragma unroll
        for (int i = 0; i < 4; i++) af[i] = *(const bf16x8*)&As[aidx[i]];
#pragma unroll
        for (int j = 0; j < 4; j++) bf[j] = *(const bf16x8*)&Bs[bidx[j]];
#pragma unroll
        for (int i = 0; i < 4; i++)
#pragma unroll
            for (int j = 0; j < 4; j++)
                acc[i][j] = __builtin_amdgcn_mfma_f32_16x16x32_bf16(
                    af[i], bf[j], acc[i][j], 0, 0, 0);
    }

    const int gm0 = bm * 128 + wm * 64;
    const int gn0 = bn * 128 + wn * 64;
#pragma unroll
    for (int j = 0; j < 4; j++) {
        int n = gn0 + j * 16 + rl;
        float sc = gamma[n] / sqrtf(var[n] + EPS_BN);
        float sh = beta[n] + (bias[n] - mean[n]) * sc;
#pragma unroll
        for (int i = 0; i < 4; i++) {
            int m0 = gm0 + i * 16 + q * 4;
#pragma unroll
            for (int t = 0; t < 4; t++) {
                float v = fmaxf(acc[i][j][t] * sc + sh, 0.f);
                out[(size_t)(m0 + t) * 256 + n] = v;
            }
        }
    }
}

// ---------------------------------------------------------------------------
// KNN phase 1 v2: branchless top-3 via fp64-packed keys.
//   key = double{hi = float_bits(d), lo = global source index}
// For finite d the double ordering == lexicographic (d, idx) ordering (incl.
// negative d, which sorts below all positives) => fmin/fmax network maintains
// exactly the stable top-3 of the bit-exact fp32 distances. No LDS, no
// branches. 8 parts x 512 sources; grid 2048 -> 8 blocks/CU.
// ---------------------------------------------------------------------------
__global__ __launch_bounds__(256) void knn_select(
    const float4* __restrict__ sxyz1,   // packed (2x,2y,2z,|s|^2) per batch
    const float4* __restrict__ txyz2,   // packed (x,y,z,|t|^2)
    double* __restrict__ cand)          // [65536][8 parts][3] keys
{
    const int tid   = threadIdx.x;
    const int blk   = blockIdx.x;        // 0..2047
    const int part  = blk & 7;
    const int chunk = (blk >> 3) & 63;
    const int b     = blk >> 9;

    const int g = b * 16384 + chunk * 256 + tid;
    const float4 T = txyz2[g];
    const float4* __restrict__ S = sxyz1 + b * 4096 + part * 512;
    const int base = part * 512;

    const double INIT = __hiloint2double(0x7F800000, 0);   // huge finite key
    double k0 = INIT, k1 = INIT, k2 = INIT;

#pragma unroll 4
    for (int i = 0; i < 512; i++) {
        float4 s = S[i];   // wave-uniform stream -> s_load
        float dot2 = __fadd_rn(__fadd_rn(__fmul_rn(T.x, s.x), __fmul_rn(T.y, s.y)),
                               __fmul_rn(T.z, s.z));            // == 2*dot exactly
        float d = __fadd_rn(__fsub_rn(T.w, dot2), s.w);
        double k  = __hiloint2double(__float_as_int(d), base + i);
        double t1 = fmax(k, k0);
        k2 = fmin(fmax(k, k1), k2);
        k1 = fmin(t1, k1);
        k0 = fmin(k, k0);
    }

    double* c = cand + (size_t)g * 24 + part * 3;
    c[0] = k0; c[1] = k1; c[2] = k2;
}

// ---------------------------------------------------------------------------
// KNN phase 2: merge 8x3 candidate keys -> final top-3 + fp32 weights.
// Keys are totally ordered (index embedded) -> plain double compares suffice.
// ---------------------------------------------------------------------------
__global__ __launch_bounds__(256) void knn_merge(
    const double* __restrict__ cand, float* __restrict__ w3,
    int* __restrict__ idx3)
{
    const int g = blockIdx.x * 256 + threadIdx.x;
    const double INIT = __hiloint2double(0x7F800000, 0);
    double k0 = INIT, k1 = INIT, k2 = INIT;
#pragma unroll
    for (int p = 0; p < 24; p++) {
        double k = cand[(size_t)g * 24 + p];
        if (k < k2) {
            if (k < k1) {
                k2 = k1;
                if (k < k0) { k1 = k0; k0 = k; }
                else        { k1 = k; }
            } else { k2 = k; }
        }
    }
    float d0 = __int_as_float(__double2hiint(k0));
    float d1 = __int_as_float(__double2hiint(k1));
    float d2 = __int_as_float(__double2hiint(k2));
    float w0 = 1.0f / __fadd_rn(d0, 1e-8f);
    float w1 = 1.0f / __fadd_rn(d1, 1e-8f);
    float w2 = 1.0f / __fadd_rn(d2, 1e-8f);
    float ws = __fadd_rn(__fadd_rn(w0, w1), w2);
    w3[(size_t)g * 3 + 0] = w0 / ws;
    w3[(size_t)g * 3 + 1] = w1 / ws;
    w3[(size_t)g * 3 + 2] = w2 / ws;
    idx3[(size_t)g * 3 + 0] = __double2loint(k0);
    idx3[(size_t)g * 3 + 1] = __double2loint(k1);
    idx3[(size_t)g * 3 + 2] = __double2loint(k2);
}

// ---------------------------------------------------------------------------
// KNN phase 3: wave-per-target gather/accumulate. out already holds feats2.
// ---------------------------------------------------------------------------
__global__ __launch_bounds__(256) void knn_gather(
    const float* __restrict__ feats1, const float* __restrict__ w3,
    const int* __restrict__ idx3, float* __restrict__ out)
{
    const int w    = threadIdx.x >> 6;
    const int lane = threadIdx.x & 63;
    const int tbase = (blockIdx.x * 4 + w) * 16;

#pragma unroll 4
    for (int k = 0; k < 16; k++) {
        const int g = tbase + k;
        const int b = g >> 14;
        const int j0 = idx3[(size_t)g * 3 + 0];
        const int j1 = idx3[(size_t)g * 3 + 1];
        const int j2 = idx3[(size_t)g * 3 + 2];
        const float u0 = w3[(size_t)g * 3 + 0];
        const float u1 = w3[(size_t)g * 3 + 1];
        const float u2 = w3[(size_t)g * 3 + 2];
        const float4* F1 = (const float4*)feats1 + (size_t)b * 4096 * 64;
        float4 f0 = F1[(size_t)j0 * 64 + lane];
        float4 f1 = F1[(size_t)j1 * 64 + lane];
        float4 f2 = F1[(size_t)j2 * 64 + lane];
        float4* O = (float4*)out + (size_t)g * 64 + lane;
        float4 o = *O;
        o.x += u0 * f0.x + u1 * f1.x + u2 * f2.x;
        o.y += u0 * f0.y + u1 * f1.y + u2 * f2.y;
        o.z += u0 * f0.z + u1 * f1.z + u2 * f2.z;
        o.w += u0 * f0.w + u1 * f1.w + u2 * f2.w;
        *O = o;
    }
}

extern "C" void kernel_launch(void* const* d_in, const int* in_sizes, int n_in,
                              void* d_out, int out_size, void* d_ws, size_t ws_size,
                              hipStream_t stream) {
    const float* xyz1    = (const float*)d_in[0];
    const float* points1 = (const float*)d_in[1];
    const float* xyz2    = (const float*)d_in[2];
    const float* points2 = (const float*)d_in[3];
    const float* W1  = (const float*)d_in[4];
    const float* b1  = (const float*)d_in[5];
    const float* g1  = (const float*)d_in[6];
    const float* be1 = (const float*)d_in[7];
    const float* m1  = (const float*)d_in[8];
    const float* v1  = (const float*)d_in[9];
    const float* W2  = (const float*)d_in[10];
    const float* b2  = (const float*)d_in[11];
    const float* g2  = (const float*)d_in[12];
    const float* be2 = (const float*)d_in[13];
    const float* m2  = (const float*)d_in[14];
    const float* v2  = (const float*)d_in[15];

    const size_t MB = 1u << 20;
    char* ws = (char*)d_ws;
    // [0,16): feats1.  [16,32): A1p, later overlaid by cand/w3/idx3 (A1p is
    // dead after gemm1; select runs after gemm1 in-stream).  [32,64): A2p.
    float*          feats1 = (float*)(ws);
    unsigned short* A1p    = (unsigned short*)(ws + 16 * MB);
    double*         cand   = (double*)(ws + 16 * MB);            // 12.6 MB
    float*          w3     = (float*)(ws + 29 * MB);             // 0.75 MB
    int*            idx3   = (int*)(ws + 30 * MB);               // 0.75 MB
    unsigned short* A2p    = (unsigned short*)(ws + 32 * MB);    // 32 MB
    unsigned short* W1p    = (unsigned short*)(ws + 64 * MB);    // 0.5 MB
    unsigned short* W2p    = (unsigned short*)(ws + 64 * MB + 512 * 1024);
    float4*         sxyz1  = (float4*)(ws + 65 * MB);            // 256 KB
    float4*         txyz2  = (float4*)(ws + 66 * MB);            // 1 MB
    float* outp = (float*)d_out;

    dim3 blk(256);
    // 1) all packing/conversion in one dispatch
    prep_all<<<12704, blk, 0, stream>>>(points1, points2, W1, W2,
                                        A1p, A2p, W1p, W2p,
                                        xyz1, xyz2, sxyz1, txyz2);
    // 2) feats1 = relu(BN(points1 @ W1^T))
    gemm_bf16_bn_relu<<<dim3(2, 128), blk, 0, stream>>>(A1p, W1p, b1, g1, be1, m1, v1,
                                                        feats1, 16384, 512);
    // 3) out = feats2 = relu(BN(points2 @ W2^T))
    gemm_bf16_bn_relu<<<dim3(2, 512), blk, 0, stream>>>(A2p, W2p, b2, g2, be2, m2, v2,
                                                        outp, 65536, 256);
    // 4-6) out += interp3(xyz2 <- xyz1, feats1)
    knn_select<<<2048, blk, 0, stream>>>(sxyz1, txyz2, cand);
    knn_merge<<<256, blk, 0, stream>>>(cand, w3, idx3);
    knn_gather<<<1024, blk, 0, stream>>>(feats1, w3, idx3, outp);
}

// Round 5
// 299.816 us; speedup vs baseline: 2.3028x; 1.2254x over previous
//
#include <hip/hip_runtime.h>
#include <math.h>

#define EPS_BN 1e-5f

typedef __attribute__((ext_vector_type(8))) short bf16x8;
typedef __attribute__((ext_vector_type(4))) float f32x4;

// ---------------------------------------------------------------------------
// async global->LDS, 16B per lane
// ---------------------------------------------------------------------------
__device__ __forceinline__ void gld_lds16(const void* g, void* l) {
    __builtin_amdgcn_global_load_lds(
        (const __attribute__((address_space(1))) unsigned int*)g,
        (__attribute__((address_space(3))) unsigned int*)l, 16, 0, 0);
}

__device__ __forceinline__ unsigned short f2bf(float f) {  // RNE fp32->bf16
    unsigned u = __float_as_uint(f);
    return (unsigned short)((u + 0x7FFFu + ((u >> 16) & 1u)) >> 16);
}

// Bit-exact fp32 distance vs np reference: sources pre-doubled so
// rn(tx*2sx) = 2*rn(tx*sx) exactly; d = rn(rn(sumT - dot2) + sumS).
__device__ __forceinline__ float dist_exact(float4 T, float4 s) {
    float dot2 = __fadd_rn(__fadd_rn(__fmul_rn(T.x, s.x), __fmul_rn(T.y, s.y)),
                           __fmul_rn(T.z, s.z));
    return __fadd_rn(__fsub_rn(T.w, dot2), s.w);
}

// ---------------------------------------------------------------------------
// fp32 [M][K] -> bf16 tile-packed swizzled: granule rotation
// g=((k>>3)+(r>>1))&3 makes MFMA fragment ds_read_b128 2-lanes/bank (free).
// ---------------------------------------------------------------------------
__device__ __forceinline__ void conv_body(
    const float* __restrict__ src, unsigned short* __restrict__ dst,
    int blk, int tid, int K8log, int nslab)
{
    const int gid = blk * 256 + tid;
    const int m  = gid >> K8log;
    const int ko = gid & ((1 << K8log) - 1);
    const float4* s = (const float4*)src + ((size_t)m << (K8log + 1)) + ko * 2;
    float4 f0 = s[0];
    float4 f1 = s[1];
    const int mblk = m >> 7, r = m & 127;
    const int slab = ko >> 2, o = ko & 3;
    const int g = (o + (r >> 1)) & 3;
    unsigned short h[8] = {f2bf(f0.x), f2bf(f0.y), f2bf(f0.z), f2bf(f0.w),
                           f2bf(f1.x), f2bf(f1.y), f2bf(f1.z), f2bf(f1.w)};
    *(uint4*)(dst + ((size_t)(mblk * nslab + slab)) * 4096 + r * 32 + g * 8) =
        *(uint4*)h;
}

// ---------------------------------------------------------------------------
// One fused prep dispatch: bf16 pack A1/A2/W1/W2 + xyz packing.
//   sxyz1[i] = (2x, 2y, 2z, |s|^2),  txyz2[i] = (x, y, z, |t|^2)
// ---------------------------------------------------------------------------
__global__ __launch_bounds__(256) void prep_all(
    const float* __restrict__ p1, const float* __restrict__ p2,
    const float* __restrict__ w1, const float* __restrict__ w2,
    unsigned short* __restrict__ A1p, unsigned short* __restrict__ A2p,
    unsigned short* __restrict__ W1p, unsigned short* __restrict__ W2p,
    const float* __restrict__ xyz1, const float* __restrict__ xyz2,
    float4* __restrict__ sxyz1, float4* __restrict__ txyz2)
{
    const int blk = blockIdx.x, tid = threadIdx.x;
    if (blk < 4096)        conv_body(p1, A1p, blk,         tid, 6, 16);
    else if (blk < 12288)  conv_body(p2, A2p, blk - 4096,  tid, 5, 8);
    else if (blk < 12352)  conv_body(w1, W1p, blk - 12288, tid, 6, 16);
    else if (blk < 12384)  conv_body(w2, W2p, blk - 12352, tid, 5, 8);
    else if (blk < 12448) {                       // xyz1 pack: 16384 sources
        int i = (blk - 12384) * 256 + tid;
        float x = xyz1[i * 3 + 0], y = xyz1[i * 3 + 1], z = xyz1[i * 3 + 2];
        float ss = __fadd_rn(__fadd_rn(__fmul_rn(x, x), __fmul_rn(y, y)),
                             __fmul_rn(z, z));
        sxyz1[i] = make_float4(x + x, y + y, z + z, ss);
    } else {                                      // xyz2 pack: 65536 targets
        int i = (blk - 12448) * 256 + tid;
        float x = xyz2[i * 3 + 0], y = xyz2[i * 3 + 1], z = xyz2[i * 3 + 2];
        float st = __fadd_rn(__fadd_rn(__fmul_rn(x, x), __fmul_rn(y, y)),
                             __fmul_rn(z, z));
        txyz2[i] = make_float4(x, y, z, st);
    }
}

// ---------------------------------------------------------------------------
// KNN phase 1 v3: quad-min scan, fp32 branchless network.
// Per quad of 4 sources: 4 exact distances -> dmin; maintain stable top-3
// (dmin, quad idx) via cmp+cndmask (strict < keeps earliest quad on ties).
// Containment: any quad with key < rank-3 single's key contains a top-3
// single, so the 3 kept quads contain all top-3 singles. Post-scan: exact
// stable re-select over the 12 candidate singles with f64-packed keys
// (hi = fp32 d bits, lo = global index) == lax.top_k stable semantics.
// ---------------------------------------------------------------------------
__global__ __launch_bounds__(256) void knn_select(
    const float4* __restrict__ sxyz1,   // packed (2x,2y,2z,|s|^2) per batch
    const float4* __restrict__ txyz2,   // packed (x,y,z,|t|^2)
    double* __restrict__ cand)          // [65536][8 parts][3] keys
{
    const int tid   = threadIdx.x;
    const int blk   = blockIdx.x;        // 0..2047
    const int part  = blk & 7;
    const int chunk = (blk >> 3) & 63;
    const int b     = blk >> 9;

    const int g = b * 16384 + chunk * 256 + tid;
    const float4 T = txyz2[g];
    const float4* __restrict__ S = sxyz1 + b * 4096 + part * 512;

    float d0 = INFINITY, d1 = INFINITY, d2 = INFINITY;
    int   q0 = 0,        q1 = 0,        q2 = 0;

#pragma unroll 2
    for (int qi = 0; qi < 128; qi++) {
        float4 sA = S[qi * 4 + 0];   // wave-uniform stream -> s_load
        float4 sB = S[qi * 4 + 1];
        float4 sC = S[qi * 4 + 2];
        float4 sD = S[qi * 4 + 3];
        float dA = dist_exact(T, sA);
        float dB = dist_exact(T, sB);
        float dC = dist_exact(T, sC);
        float dD = dist_exact(T, sD);
        float dm = fminf(fminf(dA, dB), fminf(dC, dD));

        bool c2 = dm < d2, c1 = dm < d1, c0 = dm < d0;
        float t2 = c1 ? d1 : (c2 ? dm : d2);
        int   u2 = c1 ? q1 : (c2 ? qi : q2);
        float t1 = c0 ? d0 : (c1 ? dm : d1);
        int   u1 = c0 ? q0 : (c1 ? qi : q1);
        float t0 = c0 ? dm : d0;
        int   u0 = c0 ? qi : q0;
        d2 = t2; q2 = u2; d1 = t1; q1 = u1; d0 = t0; q0 = u0;
    }

    // exact stable re-select over 12 candidate singles
    const double INIT = __hiloint2double(0x7F800000, 0);   // huge finite key
    double k0 = INIT, k1 = INIT, k2 = INIT;
#pragma unroll
    for (int c = 0; c < 3; c++) {
        const int qq = (c == 0) ? q0 : ((c == 1) ? q1 : q2);
#pragma unroll
        for (int e = 0; e < 4; e++) {
            float4 s = S[qq * 4 + e];          // divergent gather (L2-hot)
            float d = dist_exact(T, s);
            double k = __hiloint2double(__float_as_int(d),
                                        part * 512 + qq * 4 + e);
            if (k < k2) {
                if (k < k1) {
                    k2 = k1;
                    if (k < k0) { k1 = k0; k0 = k; }
                    else        { k1 = k; }
                } else { k2 = k; }
            }
        }
    }

    double* c = cand + (size_t)g * 24 + part * 3;
    c[0] = k0; c[1] = k1; c[2] = k2;
}

// ---------------------------------------------------------------------------
// KNN phase 2: merge 8x3 candidate keys -> final top-3 + fp32 weights.
// ---------------------------------------------------------------------------
__global__ __launch_bounds__(256) void knn_merge(
    const double* __restrict__ cand, float* __restrict__ w3,
    int* __restrict__ idx3)
{
    const int g = blockIdx.x * 256 + threadIdx.x;
    const double INIT = __hiloint2double(0x7F800000, 0);
    double k0 = INIT, k1 = INIT, k2 = INIT;
#pragma unroll
    for (int p = 0; p < 24; p++) {
        double k = cand[(size_t)g * 24 + p];
        if (k < k2) {
            if (k < k1) {
                k2 = k1;
                if (k < k0) { k1 = k0; k0 = k; }
                else        { k1 = k; }
            } else { k2 = k; }
        }
    }
    float d0 = __int_as_float(__double2hiint(k0));
    float d1 = __int_as_float(__double2hiint(k1));
    float d2 = __int_as_float(__double2hiint(k2));
    float w0 = 1.0f / __fadd_rn(d0, 1e-8f);
    float w1 = 1.0f / __fadd_rn(d1, 1e-8f);
    float w2 = 1.0f / __fadd_rn(d2, 1e-8f);
    float ws = __fadd_rn(__fadd_rn(w0, w1), w2);
    w3[(size_t)g * 3 + 0] = w0 / ws;
    w3[(size_t)g * 3 + 1] = w1 / ws;
    w3[(size_t)g * 3 + 2] = w2 / ws;
    idx3[(size_t)g * 3 + 0] = __double2loint(k0);
    idx3[(size_t)g * 3 + 1] = __double2loint(k1);
    idx3[(size_t)g * 3 + 2] = __double2loint(k2);
}

// ---------------------------------------------------------------------------
// bf16 MFMA GEMM + BN + ReLU (verified since R3). Used for feats1.
// ---------------------------------------------------------------------------
__global__ __launch_bounds__(256) void gemm_bf16_bn_relu(
    const unsigned short* __restrict__ Ap,
    const unsigned short* __restrict__ Bp,
    const float* __restrict__ bias,
    const float* __restrict__ gamma,
    const float* __restrict__ beta,
    const float* __restrict__ mean,
    const float* __restrict__ var,
    float* __restrict__ out, int M, int K)
{
    __shared__ __align__(16) unsigned short As[4096];
    __shared__ __align__(16) unsigned short Bs[4096];

    const int tid  = threadIdx.x;
    const int w    = tid >> 6;
    const int lane = tid & 63;
    const int q    = lane >> 4;
    const int rl   = lane & 15;
    const int wm   = w >> 1, wn = w & 1;
    const int bn   = blockIdx.x, bm = blockIdx.y;
    const int nslab = K >> 5;

    f32x4 acc[4][4];
#pragma unroll
    for (int i = 0; i < 4; i++)
#pragma unroll
        for (int j = 0; j < 4; j++) acc[i][j] = (f32x4){0.f, 0.f, 0.f, 0.f};

    const unsigned short* Ab = Ap + (size_t)bm * nslab * 4096;
    const unsigned short* Bb = Bp + (size_t)bn * nslab * 4096;
    const int c0 = 2 * w;
    const int l8 = lane * 8;

    int aidx[4], bidx[4];
#pragma unroll
    for (int i = 0; i < 4; i++) {
        int rr = wm * 64 + i * 16 + rl;
        aidx[i] = rr * 32 + ((q + (rr >> 1)) & 3) * 8;
        int nn = wn * 64 + i * 16 + rl;
        bidx[i] = nn * 32 + ((q + (nn >> 1)) & 3) * 8;
    }

    for (int s = 0; s < nslab; s++) {
        __syncthreads();
        const unsigned short* a = Ab + (size_t)s * 4096;
        const unsigned short* b = Bb + (size_t)s * 4096;
        gld_lds16(a + (c0 + 0) * 512 + l8, &As[(c0 + 0) * 512 + l8]);
        gld_lds16(a + (c0 + 1) * 512 + l8, &As[(c0 + 1) * 512 + l8]);
        gld_lds16(b + (c0 + 0) * 512 + l8, &Bs[(c0 + 0) * 512 + l8]);
        gld_lds16(b + (c0 + 1) * 512 + l8, &Bs[(c0 + 1) * 512 + l8]);
        __syncthreads();

        bf16x8 af[4], bf[4];
#pragma unroll
        for (int i = 0; i < 4; i++) af[i] = *(const bf16x8*)&As[aidx[i]];
#pragma unroll
        for (int j = 0; j < 4; j++) bf[j] = *(const bf16x8*)&Bs[bidx[j]];
#pragma unroll
        for (int i = 0; i < 4; i++)
#pragma unroll
            for (int j = 0; j < 4; j++)
                acc[i][j] = __builtin_amdgcn_mfma_f32_16x16x32_bf16(
                    af[i], bf[j], acc[i][j], 0, 0, 0);
    }

    const int gm0 = bm * 128 + wm * 64;
    const int gn0 = bn * 128 + wn * 64;
#pragma unroll
    for (int j = 0; j < 4; j++) {
        int n = gn0 + j * 16 + rl;
        float sc = gamma[n] / sqrtf(var[n] + EPS_BN);
        float sh = beta[n] + (bias[n] - mean[n]) * sc;
#pragma unroll
        for (int i = 0; i < 4; i++) {
            int m0 = gm0 + i * 16 + q * 4;
#pragma unroll
            for (int t = 0; t < 4; t++) {
                float v = fmaxf(acc[i][j][t] * sc + sh, 0.f);
                out[(size_t)(m0 + t) * 256 + n] = v;
            }
        }
    }
}

// ---------------------------------------------------------------------------
// GEMM2 + BN + ReLU + fused 3-NN interpolation add:
//   out[m][n] = relu(BN(A2@W2^T)) + sum_k w3[m][k] * feats1[b(m), idx3[m][k]][n]
// Same GEMM core; epilogue gathers feats1 rows (64B-coalesced per 16-lane
// group) and adds before the single store — kills the 128 MB out RMW.
// ---------------------------------------------------------------------------
__global__ __launch_bounds__(256) void gemm2_interp(
    const unsigned short* __restrict__ Ap,
    const unsigned short* __restrict__ Bp,
    const float* __restrict__ bias,
    const float* __restrict__ gamma,
    const float* __restrict__ beta,
    const float* __restrict__ mean,
    const float* __restrict__ var,
    const float* __restrict__ feats1,   // [4*4096][256]
    const float* __restrict__ w3,       // [65536][3]
    const int*   __restrict__ idx3,     // [65536][3] (within-batch indices)
    float* __restrict__ out)
{
    __shared__ __align__(16) unsigned short As[4096];
    __shared__ __align__(16) unsigned short Bs[4096];

    const int tid  = threadIdx.x;
    const int w    = tid >> 6;
    const int lane = tid & 63;
    const int q    = lane >> 4;
    const int rl   = lane & 15;
    const int wm   = w >> 1, wn = w & 1;
    const int bn   = blockIdx.x, bm = blockIdx.y;
    const int nslab = 8;                 // K = 256

    f32x4 acc[4][4];
#pragma unroll
    for (int i = 0; i < 4; i++)
#pragma unroll
        for (int j = 0; j < 4; j++) acc[i][j] = (f32x4){0.f, 0.f, 0.f, 0.f};

    const unsigned short* Ab = Ap + (size_t)bm * nslab * 4096;
    const unsigned short* Bb = Bp + (size_t)bn * nslab * 4096;
    const int c0 = 2 * w;
    const int l8 = lane * 8;

    int aidx[4], bidx[4];
#pragma unroll
    for (int i = 0; i < 4; i++) {
        int rr = wm * 64 + i * 16 + rl;
        aidx[i] = rr * 32 + ((q + (rr >> 1)) & 3) * 8;
        int nn = wn * 64 + i * 16 + rl;
        bidx[i] = nn * 32 + ((q + (nn >> 1)) & 3) * 8;
    }

    for (int s = 0; s < nslab; s++) {
        __syncthreads();
        const unsigned short* a = Ab + (size_t)s * 4096;
        const unsigned short* b = Bb + (size_t)s * 4096;
        gld_lds16(a + (c0 + 0) * 512 + l8, &As[(c0 + 0) * 512 + l8]);
        gld_lds16(a + (c0 + 1) * 512 + l8, &As[(c0 + 1) * 512 + l8]);
        gld_lds16(b + (c0 + 0) * 512 + l8, &Bs[(c0 + 0) * 512 + l8]);
        gld_lds16(b + (c0 + 1) * 512 + l8, &Bs[(c0 + 1) * 512 + l8]);
        __syncthreads();

        bf16x8 af[4], bf[4];
#pragma unroll
        for (int i = 0; i < 4; i++) af[i] = *(const bf16x8*)&As[aidx[i]];
#pragma unroll
        for (int j = 0; j < 4; j++) bf[j] = *(const bf16x8*)&Bs[bidx[j]];
#pragma unroll
        for (int i = 0; i < 4; i++)
#pragma unroll
            for (int j = 0; j < 4; j++)
                acc[i][j] = __builtin_amdgcn_mfma_f32_16x16x32_bf16(
                    af[i], bf[j], acc[i][j], 0, 0, 0);
    }

    const int gm0 = bm * 128 + wm * 64;
    const int gn0 = bn * 128 + wn * 64;
    float scj[4], shj[4];
    int nj[4];
#pragma unroll
    for (int j = 0; j < 4; j++) {
        int n = gn0 + j * 16 + rl;
        nj[j] = n;
        float sc = gamma[n] / sqrtf(var[n] + EPS_BN);
        scj[j] = sc;
        shj[j] = beta[n] + (bias[n] - mean[n]) * sc;
    }

#pragma unroll
    for (int i = 0; i < 4; i++) {
#pragma unroll
        for (int t = 0; t < 4; t++) {
            const int m = gm0 + i * 16 + q * 4 + t;      // global target row
            const int bb = m >> 14;                      // batch
            const int j0 = idx3[(size_t)m * 3 + 0];
            const int j1 = idx3[(size_t)m * 3 + 1];
            const int j2 = idx3[(size_t)m * 3 + 2];
            const float u0 = w3[(size_t)m * 3 + 0];
            const float u1 = w3[(size_t)m * 3 + 1];
            const float u2 = w3[(size_t)m * 3 + 2];
            const float* f0 = feats1 + ((size_t)(bb * 4096 + j0)) * 256;
            const float* f1 = feats1 + ((size_t)(bb * 4096 + j1)) * 256;
            const float* f2 = feats1 + ((size_t)(bb * 4096 + j2)) * 256;
#pragma unroll
            for (int j = 0; j < 4; j++) {
                const int n = nj[j];
                float v = fmaxf(acc[i][j][t] * scj[j] + shj[j], 0.f);
                v += u0 * f0[n] + u1 * f1[n] + u2 * f2[n];
                out[(size_t)m * 256 + n] = v;
            }
        }
    }
}

extern "C" void kernel_launch(void* const* d_in, const int* in_sizes, int n_in,
                              void* d_out, int out_size, void* d_ws, size_t ws_size,
                              hipStream_t stream) {
    const float* xyz1    = (const float*)d_in[0];
    const float* points1 = (const float*)d_in[1];
    const float* xyz2    = (const float*)d_in[2];
    const float* points2 = (const float*)d_in[3];
    const float* W1  = (const float*)d_in[4];
    const float* b1  = (const float*)d_in[5];
    const float* g1  = (const float*)d_in[6];
    const float* be1 = (const float*)d_in[7];
    const float* m1  = (const float*)d_in[8];
    const float* v1  = (const float*)d_in[9];
    const float* W2  = (const float*)d_in[10];
    const float* b2  = (const float*)d_in[11];
    const float* g2  = (const float*)d_in[12];
    const float* be2 = (const float*)d_in[13];
    const float* m2  = (const float*)d_in[14];
    const float* v2  = (const float*)d_in[15];

    const size_t MB = 1u << 20;
    char* ws = (char*)d_ws;
    // cand lives in [0,16)MB, dead before gemm1 writes feats1 there.
    float*          feats1 = (float*)(ws);                       // 16 MB
    double*         cand   = (double*)(ws);                      // 12.6 MB
    unsigned short* A1p    = (unsigned short*)(ws + 16 * MB);    // 16 MB
    unsigned short* A2p    = (unsigned short*)(ws + 32 * MB);    // 32 MB
    unsigned short* W1p    = (unsigned short*)(ws + 64 * MB);    // 0.5 MB
    unsigned short* W2p    = (unsigned short*)(ws + 64 * MB + 512 * 1024);
    float4*         sxyz1  = (float4*)(ws + 65 * MB);            // 256 KB
    float4*         txyz2  = (float4*)(ws + 66 * MB);            // 1 MB
    float*          w3     = (float*)(ws + 67 * MB);             // 0.75 MB
    int*            idx3   = (int*)(ws + 68 * MB);               // 0.75 MB
    float* outp = (float*)d_out;

    dim3 blk(256);
    // 1) all packing/conversion in one dispatch
    prep_all<<<12704, blk, 0, stream>>>(points1, points2, W1, W2,
                                        A1p, A2p, W1p, W2p,
                                        xyz1, xyz2, sxyz1, txyz2);
    // 2-3) neighbor selection (independent of GEMMs)
    knn_select<<<2048, blk, 0, stream>>>(sxyz1, txyz2, cand);
    knn_merge<<<256, blk, 0, stream>>>(cand, w3, idx3);
    // 4) feats1 = relu(BN(points1 @ W1^T))   (clobbers cand — cand is dead)
    gemm_bf16_bn_relu<<<dim3(2, 128), blk, 0, stream>>>(A1p, W1p, b1, g1, be1, m1, v1,
                                                        feats1, 16384, 512);
    // 5) out = relu(BN(points2 @ W2^T)) + interp3(xyz2 <- xyz1, feats1)
    gemm2_interp<<<dim3(2, 512), blk, 0, stream>>>(A2p, W2p, b2, g2, be2, m2, v2,
                                                   feats1, w3, idx3, outp);
}